// Round 15
// baseline (94.138 us; speedup 1.0000x reference)
//
#include <hip/hip_runtime.h>
#include <hip/hip_fp16.h>

// DynamicGaussianBlur: [B=4, D=160, H=160, W=160, C=2] fp32, sigma [4,3],
// separable 3D gaussian, window 13 (radius 6), SAME zero padding.
// Two passes; ws is FP16 (half2 = channel pair):
//   A: D-blur register line-walk, float4-wide, SEGA=20/NSEGA=8 for ~25
//      waves/CU (halo re-reads are L3-hot).               in -> ws(fp16)
//   B: fused H+W blur per (b,d,h-tile); slab + hbuf kept FP16 in LDS
//      (20,480 B -> 6 blocks/CU); OUT stores nontemporal. ws -> out

#define WSZ 13
#define RAD 6
#define SEGA 20       // pass A: d-segment per thread
#define NSEGA 8

typedef float nfloat2 __attribute__((ext_vector_type(2)));   // nt-capable float2

constexpr int BB = 4, DD = 160, HH = 160, WW = 160;
constexpr int R2 = 160;             // row in float2 / half2 units
constexpr int P2 = HH * WW;         // plane (25,600)
constexpr int N2 = DD * P2;         // batch volume
constexpr int P4 = P2 / 2;          // plane in float4 / uint2 units (12,800)
constexpr int N4 = N2 / 2;
constexpr int NCOL4 = BB * P4;      // pass-A float4 columns (51,200)

// Pass B tile
#define TB 20
#define SLABR (TB + 12)              // 32 slab rows x 160 half2 = 20,480 B LDS
#define HBS 172                      // hbuf row stride (half2 units)

__device__ __forceinline__ void make_weights(float sig, float* w) {
    const float invd = 1.0f / (2.0f * sig * sig + 1e-7f);
    float s = 0.0f;
#pragma unroll
    for (int k = 0; k < WSZ; ++k) {
        const float loc = (float)(k - RAD);
        w[k] = __expf(-loc * loc * invd);
        s += w[k];
    }
    const float inv = 1.0f / s;
#pragma unroll
    for (int k = 0; k < WSZ; ++k) w[k] *= inv;
}

// ---------------- Pass A: D-blur register walk, float4-wide, fp16 ws ----------------
__global__ __launch_bounds__(256) void blur_d(const float2* __restrict__ in,
                                              __half2* __restrict__ ws,
                                              const float* __restrict__ sigma) {
    const float4* in4 = (const float4*)in;
    uint2* wsU = (uint2*)ws;

    const int cid = blockIdx.x * 256 + threadIdx.x;   // float4-column id
    const int b   = cid / P4;                         // uniform per block
    const int rem = cid % P4;                         // position within plane (f4 units)

    float wgt[WSZ];
    make_weights(sigma[b * 3 + 0], wgt);

    const int ibase = b * N4 + rem;                   // float4 index at d=0
    const int obase = b * N4 + rem;                   // uint2 index at d=0
    const int p0 = blockIdx.y * SEGA;

    float4 win[WSZ];
#pragma unroll
    for (int k = 0; k < WSZ; ++k) {
        const int q = p0 - RAD + k;
        float4 v = make_float4(0.f, 0.f, 0.f, 0.f);
        if (q >= 0 && q < DD) v = in4[ibase + q * P4];
        win[k] = v;
    }

#pragma unroll 4
    for (int i = 0; i < SEGA; ++i) {
        float ax0 = 0.f, ay0 = 0.f, ax1 = 0.f, ay1 = 0.f;
#pragma unroll
        for (int k = 0; k < WSZ; ++k) {
            const float4 v = win[k];
            ax0 += wgt[k] * v.x; ay0 += wgt[k] * v.y;
            ax1 += wgt[k] * v.z; ay1 += wgt[k] * v.w;
        }
        union { uint2 u; __half2 h[2]; } o;
        o.h[0] = __float22half2_rn(make_float2(ax0, ay0));
        o.h[1] = __float22half2_rn(make_float2(ax1, ay1));
        wsU[obase + (p0 + i) * P4] = o.u;             // normal store: keep ws in L3

#pragma unroll
        for (int k = 0; k < WSZ - 1; ++k) win[k] = win[k + 1];
        const int q = p0 + i + RAD + 1;
        float4 v = make_float4(0.f, 0.f, 0.f, 0.f);
        if (q < DD) v = in4[ibase + q * P4];
        win[WSZ - 1] = v;
    }
}

// ---------------- Pass B: fused H+W blur, fp16 LDS, one (b,d,h-tile) per block ----------------
__global__ __launch_bounds__(320) void blur_hw(const __half2* __restrict__ ws,
                                               float2* __restrict__ out,
                                               const float* __restrict__ sigma) {
    __shared__ __align__(16) __half2 lds[SLABR * R2];   // 20,480 B

    const int tid  = threadIdx.x;
    const int bx   = blockIdx.x;
    const int tile = bx & 7;                 // 8 h-tiles of 20 rows
    const int d    = (bx >> 3) % DD;
    const int b    = bx / (8 * DD);
    const int h0   = tile * TB;

    float wh[WSZ];
    make_weights(sigma[b * 3 + 1], wh);

    // ---- stage slab rows h0-6 .. h0+25 (32 x 160 half2) raw fp16: 4 f4/thread ----
    const float4* p4 = (const float4*)(ws + b * N2 + d * P2);   // 40 f4 per fp16 row
    float4* l4 = (float4*)lds;
#pragma unroll
    for (int j = 0; j < 4; ++j) {
        const int f = j * 320 + tid;                   // 0..1279
        const int r = f / 40, q = f % 40;
        const int hh = h0 - 6 + r;
        float4 v = make_float4(0.f, 0.f, 0.f, 0.f);
        if (hh >= 0 && hh < HH) v = p4[hh * 40 + q];
        l4[f] = v;
    }
    __syncthreads();

    // ---- H-blur: one column-walk per thread (cvt fp16->f32 at read) ----
    float2 o[10];
    {
        const int w  = tid % 160;
        const int r0 = (tid / 160) * 10;
        float2 win[WSZ];
#pragma unroll
        for (int k = 0; k < WSZ - 1; ++k) win[k] = __half22float2(lds[(r0 + k) * R2 + w]);
#pragma unroll
        for (int i = 0; i < 10; ++i) {
            win[WSZ - 1] = __half22float2(lds[(r0 + i + WSZ - 1) * R2 + w]);
            float ax = 0.0f, ay = 0.0f;
#pragma unroll
            for (int k = 0; k < WSZ; ++k) { ax += wh[k] * win[k].x; ay += wh[k] * win[k].y; }
            o[i] = make_float2(ax, ay);
#pragma unroll
            for (int k = 0; k < WSZ - 1; ++k) win[k] = win[k + 1];
        }
    }
    __syncthreads();   // all slab reads done; reuse LDS as fp16 hbuf[20][172]

    // ---- write hbuf (fp16): zero stripes + data shifted +6 ----
    __half2* hb = lds;
    if (tid < 240) {
        const int r = tid / 12, c = tid % 12;
        const int col = (c < 6) ? c : (160 + c);
        hb[r * HBS + col] = __half2(__float2half(0.f), __float2half(0.f));
    }
    {
        const int w  = tid % 160;
        const int r0 = (tid / 160) * 10;
#pragma unroll
        for (int i = 0; i < 10; ++i) hb[(r0 + i) * HBS + 6 + w] = __float22half2_rn(o[i]);
    }
    __syncthreads();

    // ---- W-blur: 3200 outputs, coalesced NONTEMPORAL stores ----
    float ww[WSZ];
    make_weights(sigma[b * 3 + 2], ww);

    nfloat2* oplane = (nfloat2*)(out + b * N2 + d * P2 + h0 * R2);
#pragma unroll
    for (int j = 0; j < 10; ++j) {
        const int oidx = j * 320 + tid;
        const int r = oidx / 160, w = oidx % 160;
        const __half2* src = &hb[r * HBS + w];
        float ax = 0.0f, ay = 0.0f;
#pragma unroll
        for (int k = 0; k < WSZ; ++k) {
            const float2 v = __half22float2(src[k]);
            ax += ww[k] * v.x; ay += ww[k] * v.y;
        }
        nfloat2 res; res.x = ax; res.y = ay;
        __builtin_nontemporal_store(res, &oplane[oidx]);
    }
}

extern "C" void kernel_launch(void* const* d_in, const int* in_sizes, int n_in,
                              void* d_out, int out_size, void* d_ws, size_t ws_size,
                              hipStream_t stream) {
    const float2* img   = (const float2*)d_in[0];
    const float*  sigma = (const float*)d_in[1];
    float2*  out = (float2*)d_out;
    __half2* ws  = (__half2*)d_ws;

    blur_d<<<dim3(NCOL4 / 256, NSEGA), dim3(256), 0, stream>>>(img, ws, sigma);
    blur_hw<<<dim3(BB * DD * 8), dim3(320), 0, stream>>>(ws, out, sigma);
}

// Round 16
// 82.973 us; speedup vs baseline: 1.1346x; 1.1346x over previous
//
#include <hip/hip_runtime.h>
#include <hip/hip_fp16.h>

// DynamicGaussianBlur: [B=4, D=160, H=160, W=160, C=2] fp32, sigma [4,3],
// separable 3D gaussian, window 13 (radius 6), SAME zero padding.
// Two passes; ws is FP16 (half2 = channel pair):
//   A: D-blur register line-walk, float4-wide (16B loads, 8B packed
//      half2x2 stores), SEGA=40/NSEGA=4.                   in -> ws(fp16)
//   B: fused H+W blur per (b,d,h-tile); UNION LDS: fp16 slab (20,480 B)
//      for staging+H-blur, reused as f32 hbuf (27,520 B) for W-blur.
//      27.5 KB -> 5 blocks/CU. OUT stores nontemporal.     ws -> out

#define WSZ 13
#define RAD 6
#define SEGA 40       // pass A: d-segment per thread
#define NSEGA 4

typedef float nfloat2 __attribute__((ext_vector_type(2)));   // nt-capable float2

constexpr int BB = 4, DD = 160, HH = 160, WW = 160;
constexpr int R2 = 160;             // row in float2 / half2 units
constexpr int P2 = HH * WW;         // plane (25,600)
constexpr int N2 = DD * P2;         // batch volume
constexpr int P4 = P2 / 2;          // plane in float4 / uint2 units (12,800)
constexpr int N4 = N2 / 2;
constexpr int NCOL4 = BB * P4;      // pass-A float4 columns (51,200)

// Pass B tile
#define TB 20
#define SLABR (TB + 12)              // 32 slab rows (fp16: 20,480 B)
#define HBS 172                      // hbuf row stride (float2 units)
#define SMEM_BYTES (TB * HBS * 8)    // 27,520 B (f32 hbuf is the max)

__device__ __forceinline__ void make_weights(float sig, float* w) {
    const float invd = 1.0f / (2.0f * sig * sig + 1e-7f);
    float s = 0.0f;
#pragma unroll
    for (int k = 0; k < WSZ; ++k) {
        const float loc = (float)(k - RAD);
        w[k] = __expf(-loc * loc * invd);
        s += w[k];
    }
    const float inv = 1.0f / s;
#pragma unroll
    for (int k = 0; k < WSZ; ++k) w[k] *= inv;
}

// ---------------- Pass A: D-blur register walk, float4-wide, fp16 ws ----------------
__global__ __launch_bounds__(256) void blur_d(const float2* __restrict__ in,
                                              __half2* __restrict__ ws,
                                              const float* __restrict__ sigma) {
    const float4* in4 = (const float4*)in;
    uint2* wsU = (uint2*)ws;

    const int cid = blockIdx.x * 256 + threadIdx.x;   // float4-column id
    const int b   = cid / P4;                         // uniform per block
    const int rem = cid % P4;                         // position within plane (f4 units)

    float wgt[WSZ];
    make_weights(sigma[b * 3 + 0], wgt);

    const int ibase = b * N4 + rem;                   // float4 index at d=0
    const int obase = b * N4 + rem;                   // uint2 index at d=0
    const int p0 = blockIdx.y * SEGA;

    float4 win[WSZ];
#pragma unroll
    for (int k = 0; k < WSZ; ++k) {
        const int q = p0 - RAD + k;
        float4 v = make_float4(0.f, 0.f, 0.f, 0.f);
        if (q >= 0 && q < DD) v = in4[ibase + q * P4];
        win[k] = v;
    }

#pragma unroll 4
    for (int i = 0; i < SEGA; ++i) {
        float ax0 = 0.f, ay0 = 0.f, ax1 = 0.f, ay1 = 0.f;
#pragma unroll
        for (int k = 0; k < WSZ; ++k) {
            const float4 v = win[k];
            ax0 += wgt[k] * v.x; ay0 += wgt[k] * v.y;
            ax1 += wgt[k] * v.z; ay1 += wgt[k] * v.w;
        }
        union { uint2 u; __half2 h[2]; } o;
        o.h[0] = __float22half2_rn(make_float2(ax0, ay0));
        o.h[1] = __float22half2_rn(make_float2(ax1, ay1));
        wsU[obase + (p0 + i) * P4] = o.u;             // normal store: keep ws in L3

#pragma unroll
        for (int k = 0; k < WSZ - 1; ++k) win[k] = win[k + 1];
        const int q = p0 + i + RAD + 1;
        float4 v = make_float4(0.f, 0.f, 0.f, 0.f);
        if (q < DD) v = in4[ibase + q * P4];
        win[WSZ - 1] = v;
    }
}

// ---------------- Pass B: fused H+W blur, union LDS, one (b,d,h-tile) per block ----------------
__global__ __launch_bounds__(320) void blur_hw(const __half2* __restrict__ ws,
                                               float2* __restrict__ out,
                                               const float* __restrict__ sigma) {
    __shared__ __align__(16) unsigned char smem[SMEM_BYTES];   // 27,520 B union
    __half2* slab = (__half2*)smem;            // phase 1: fp16 slab [SLABR][R2]
    float2*  hb   = (float2*)smem;             // phase 2: f32 hbuf [TB][HBS]

    const int tid  = threadIdx.x;
    const int bx   = blockIdx.x;
    const int tile = bx & 7;                 // 8 h-tiles of 20 rows
    const int d    = (bx >> 3) % DD;
    const int b    = bx / (8 * DD);
    const int h0   = tile * TB;

    float wh[WSZ];
    make_weights(sigma[b * 3 + 1], wh);

    // ---- stage slab rows h0-6 .. h0+25 (32 x 160 half2) raw fp16: 4 f4/thread ----
    const float4* p4 = (const float4*)(ws + b * N2 + d * P2);   // 40 f4 per fp16 row
    float4* l4 = (float4*)smem;
#pragma unroll
    for (int j = 0; j < 4; ++j) {
        const int f = j * 320 + tid;                   // 0..1279
        const int r = f / 40, q = f % 40;
        const int hh = h0 - 6 + r;
        float4 v = make_float4(0.f, 0.f, 0.f, 0.f);
        if (hh >= 0 && hh < HH) v = p4[hh * 40 + q];
        l4[f] = v;
    }
    __syncthreads();

    // ---- H-blur: one column-walk per thread (cvt fp16->f32 at read) ----
    float2 o[10];
    {
        const int w  = tid % 160;
        const int r0 = (tid / 160) * 10;
        float2 win[WSZ];
#pragma unroll
        for (int k = 0; k < WSZ - 1; ++k) win[k] = __half22float2(slab[(r0 + k) * R2 + w]);
#pragma unroll
        for (int i = 0; i < 10; ++i) {
            win[WSZ - 1] = __half22float2(slab[(r0 + i + WSZ - 1) * R2 + w]);
            float ax = 0.0f, ay = 0.0f;
#pragma unroll
            for (int k = 0; k < WSZ; ++k) { ax += wh[k] * win[k].x; ay += wh[k] * win[k].y; }
            o[i] = make_float2(ax, ay);
#pragma unroll
            for (int k = 0; k < WSZ - 1; ++k) win[k] = win[k + 1];
        }
    }
    __syncthreads();   // all slab reads done; reuse LDS as f32 hbuf[20][172]

    // ---- write hbuf (f32): zero stripes + data shifted +6 ----
    if (tid < 240) {
        const int r = tid / 12, c = tid % 12;
        const int col = (c < 6) ? c : (160 + c);
        hb[r * HBS + col] = make_float2(0.0f, 0.0f);
    }
    {
        const int w  = tid % 160;
        const int r0 = (tid / 160) * 10;
#pragma unroll
        for (int i = 0; i < 10; ++i) hb[(r0 + i) * HBS + 6 + w] = o[i];
    }
    __syncthreads();

    // ---- W-blur: 3200 outputs, pure f32 FMA, coalesced NONTEMPORAL stores ----
    float ww[WSZ];
    make_weights(sigma[b * 3 + 2], ww);

    nfloat2* oplane = (nfloat2*)(out + b * N2 + d * P2 + h0 * R2);
#pragma unroll
    for (int j = 0; j < 10; ++j) {
        const int oidx = j * 320 + tid;
        const int r = oidx / 160, w = oidx % 160;
        const float2* src = &hb[r * HBS + w];
        float ax = 0.0f, ay = 0.0f;
#pragma unroll
        for (int k = 0; k < WSZ; ++k) { const float2 v = src[k]; ax += ww[k] * v.x; ay += ww[k] * v.y; }
        nfloat2 res; res.x = ax; res.y = ay;
        __builtin_nontemporal_store(res, &oplane[oidx]);
    }
}

extern "C" void kernel_launch(void* const* d_in, const int* in_sizes, int n_in,
                              void* d_out, int out_size, void* d_ws, size_t ws_size,
                              hipStream_t stream) {
    const float2* img   = (const float2*)d_in[0];
    const float*  sigma = (const float*)d_in[1];
    float2*  out = (float2*)d_out;
    __half2* ws  = (__half2*)d_ws;

    blur_d<<<dim3(NCOL4 / 256, NSEGA), dim3(256), 0, stream>>>(img, ws, sigma);
    blur_hw<<<dim3(BB * DD * 8), dim3(320), 0, stream>>>(ws, out, sigma);
}